// Round 8
// baseline (152.729 us; speedup 1.0000x reference)
//
#include <hip/hip_runtime.h>
#include <hip/hip_bf16.h>

// Problem constants: E=4 edge types, B=262144 tokens, C=128 dim
#define N_E 4
#define N_B 262144
#define N_C 128

typedef __attribute__((ext_vector_type(8))) short bf16x8;   // MFMA A/B frag (8 bf16)
typedef __attribute__((ext_vector_type(4))) float f32x4;    // MFMA C/D frag
typedef __attribute__((ext_vector_type(4))) unsigned int u32x4;

// pack two fp32 -> u32 of 2 bf16 (RNE) via v_cvt_pk_bf16_f32
__device__ __forceinline__ unsigned pk2(float lo, float hi) {
  float2 t; t.x = lo; t.y = hi;
  __hip_bfloat162 h = __float22bfloat162_rn(t);
  union { __hip_bfloat162 h; unsigned u; } c;
  c.h = h;
  return c.u;
}

// out[b][d] = sum_e sum_c xs[e][b][c]*Ws[e][c][d] + sum_e bs[e][d]
// M=262144, N=128, K=512; memory-bound.
//
// R1-R7 all swept each 512B row in FOUR separate 128B passes (kt inner) ->
// every HBM page activated ~4x, 25% drained per activation. Hypothesis: page-
// activation rate caps read BW at ~4.6 TB/s. This round: SINGLE-PASS reads.
// k-bijection remap (applied to both A and W): lane (l15,hi) owns contiguous
// k-window [hi*32, hi*32+32) of its row, fetched as 8 back-to-back dwordx4
// from ONE base (row*512 + hi*128, offsets 0..112). Per e-phase a wave reads
// its 16rows x 512B = 8KB region densely in one burst; each page opened once.
// MFMA step kt uses regs {2kt,2kt+1}: fragment k-slot (hi,j) = hi*32+kt*8+j;
// W LDS layout permuted identically. 2-phase register double buffer (64 VGPR),
// waits vmcnt(14/12/10/8), tail 6/4/2/0 (hand-simulated). Bias in LDS.
// Everything else (grid, block, W-resident LDS, epilogue) = R4.
__global__ void __launch_bounds__(1024, 4)
grouped_gemm(const float* __restrict__ xs, const float* __restrict__ Ws,
             const float* __restrict__ bs, float* __restrict__ out) {
  extern __shared__ unsigned char smem[];
  unsigned short* lds_w    = (unsigned short*)smem;    // 8192 entries * 16B = 128 KiB
  float*          lds_bias = (float*)(smem + 131072);  // 512 B

  const int tid  = threadIdx.x;
  const int lane = tid & 63;
  const int wave = tid >> 6;       // 0..15
  const int l15  = lane & 15;
  const int hi   = lane >> 4;
  const int waveRow = blockIdx.x * 256 + wave * 16;

  // ---- stage ALL W (4x128x128 fp32) -> LDS bf16, k-permuted fragment layout ----
  // entry m: e=m>>11, g=(m>>7)&15 (g=kt*4+h2), d=m&127; 8 shorts j=0..7 hold
  // W[e][h2*32 + kt*8 + j][d]  (matches the A k-map: contiguous per-lane k-window)
#pragma unroll
  for (int i = 0; i < 8; ++i) {
    int m = tid + i * 1024;
    int e = m >> 11;
    int g = (m >> 7) & 15;
    int d = m & 127;
    int kt = g >> 2, h2 = g & 3;
    const float* src = Ws + e * (N_C * N_C) + (h2 * 32 + kt * 8) * N_C + d;
    float v[8];
#pragma unroll
    for (int j = 0; j < 8; ++j) v[j] = src[j * N_C];  // rows h2*32+kt*8 .. +7
    u32x4 pk;
#pragma unroll
    for (int j = 0; j < 4; ++j) pk[j] = pk2(v[2 * j], v[2 * j + 1]);
    *reinterpret_cast<u32x4*>(&lds_w[(size_t)m * 8]) = pk;
  }
  if (tid < 128) {
    lds_bias[tid] = bs[tid] + bs[128 + tid] + bs[256 + tid] + bs[384 + tid];
  }

  // Drain ALL compiler-emitted vmem so loop vmcnt counts are exact.
  asm volatile("s_waitcnt vmcnt(0)" ::: "memory");
  __syncthreads();  // the only barrier

  // ---- A stream: lane (l15,hi) reads bytes [hi*128, hi*128+128) of its row ----
  const unsigned vb = (unsigned)(waveRow + l15) * 512u + (unsigned)hi * 128u;
  const unsigned long long xbase = (unsigned long long)xs;

  f32x4 A[2][8];  // 2-phase double buffer; indexed only with compile-time constants

  // AISSUE(e): 8 back-to-back dwordx4 covering the lane's contiguous 128B for
  // edge e -> wave covers its 8KB region densely (page opened once).
#define AISSUE(e)                                                              \
  do {                                                                         \
    unsigned o;                                                                \
    asm volatile("v_add_u32 %0, %1, %2"                                        \
                 : "=v"(o) : "n"((e) * 134217728u), "v"(vb));                  \
    asm volatile("global_load_dwordx4 %0, %8, %9 offset:0\n\t"                 \
                 "global_load_dwordx4 %1, %8, %9 offset:16\n\t"                \
                 "global_load_dwordx4 %2, %8, %9 offset:32\n\t"                \
                 "global_load_dwordx4 %3, %8, %9 offset:48\n\t"                \
                 "global_load_dwordx4 %4, %8, %9 offset:64\n\t"                \
                 "global_load_dwordx4 %5, %8, %9 offset:80\n\t"                \
                 "global_load_dwordx4 %6, %8, %9 offset:96\n\t"                \
                 "global_load_dwordx4 %7, %8, %9 offset:112"                   \
                 : "=&v"(A[(e) & 1][0]), "=&v"(A[(e) & 1][1]),                 \
                   "=&v"(A[(e) & 1][2]), "=&v"(A[(e) & 1][3]),                 \
                   "=&v"(A[(e) & 1][4]), "=&v"(A[(e) & 1][5]),                 \
                   "=&v"(A[(e) & 1][6]), "=&v"(A[(e) & 1][7])                  \
                 : "v"(o), "s"(xbase)                                          \
                 : "memory");                                                  \
  } while (0)

#define WAITV(n)                                          \
  do {                                                    \
    asm volatile("s_waitcnt vmcnt(" #n ")" ::: "memory"); \
    __builtin_amdgcn_sched_barrier(0);                    \
  } while (0)

  f32x4 acc[8];
#pragma unroll
  for (int n = 0; n < 8; ++n) {
    f32x4 z = {0.0f, 0.0f, 0.0f, 0.0f};
    acc[n] = z;
  }

  // KT(e,kt,w): wait loads {2kt,2kt+1} of phase e (vmcnt w), cvt, 8 MFMA.
  // afrag slot j = x[k = hi*32 + kt*8 + j]; bfrag slot j = W[same k][d].
#define KT(e, kt, w)                                                           \
  do {                                                                         \
    WAITV(w);                                                                  \
    f32x4 a0 = A[(e) & 1][2 * (kt)];                                           \
    f32x4 a1 = A[(e) & 1][2 * (kt) + 1];                                       \
    bf16x8 afrag;                                                              \
    unsigned* au = reinterpret_cast<unsigned*>(&afrag);                        \
    au[0] = pk2(a0[0], a0[1]);                                                 \
    au[1] = pk2(a0[2], a0[3]);                                                 \
    au[2] = pk2(a1[0], a1[1]);                                                 \
    au[3] = pk2(a1[2], a1[3]);                                                 \
    const unsigned short* wb =                                                 \
        lds_w + (size_t)((((e) * 4 + (kt)) * 4 + hi) * 128 + l15) * 8;         \
    _Pragma("unroll")                                                          \
    for (int n = 0; n < 8; ++n) {                                              \
      bf16x8 bfrag = *reinterpret_cast<const bf16x8*>(wb + (size_t)n * 128);   \
      acc[n] = __builtin_amdgcn_mfma_f32_16x16x32_bf16(afrag, bfrag, acc[n], 0, 0, 0); \
    }                                                                          \
  } while (0)

  AISSUE(0); AISSUE(1);
  // phase e0: queue = [E0:8, E1:8]; need 2 oldest per kt
  KT(0, 0, 14); KT(0, 1, 12); KT(0, 2, 10); KT(0, 3, 8);
  AISSUE(2);  // refills buf0 (E0 fully consumed by kt3's cvt)
  KT(1, 0, 14); KT(1, 1, 12); KT(1, 2, 10); KT(1, 3, 8);
  AISSUE(3);
  KT(2, 0, 14); KT(2, 1, 12); KT(2, 2, 10); KT(2, 3, 8);
  // phase e3: queue = [E3:8], no more issues -> drain
  KT(3, 0, 6);  KT(3, 1, 4);  KT(3, 2, 2);  KT(3, 3, 0);

#undef KT
#undef WAITV
#undef AISSUE

  // ---- epilogue: + bias (LDS), store. C/D: col=lane&15, row=(lane>>4)*4+reg ----
#pragma unroll
  for (int n = 0; n < 8; ++n) {
    int d = n * 16 + l15;
    float bias = lds_bias[d];
#pragma unroll
    for (int r = 0; r < 4; ++r) {
      int row = waveRow + hi * 4 + r;
      out[(size_t)row * N_C + d] = acc[n][r] + bias;
    }
  }
}

extern "C" void kernel_launch(void* const* d_in, const int* in_sizes, int n_in,
                              void* d_out, int out_size, void* d_ws, size_t ws_size,
                              hipStream_t stream) {
  const float* xs = (const float*)d_in[0];  // [4][262144][128] fp32
  const float* Ws = (const float*)d_in[1];  // [4][128][128] fp32
  const float* bs = (const float*)d_in[2];  // [4][128] fp32
  float* out = (float*)d_out;               // [262144][128] fp32

  const size_t smem = 131072 + 512;  // W frag layout + bias
  hipFuncSetAttribute((const void*)grouped_gemm,
                      hipFuncAttributeMaxDynamicSharedMemorySize, (int)smem);

  dim3 grid(N_B / 256);   // 1024 blocks (256 rows each)
  dim3 block(1024);       // 16 waves/CU (VGPR capped at 128)
  hipLaunchKernelGGL(grouped_gemm, grid, block, smem, stream, xs, Ws, bs, out);
}

// Round 9
// 146.872 us; speedup vs baseline: 1.0399x; 1.0399x over previous
//
#include <hip/hip_runtime.h>
#include <hip/hip_bf16.h>

// Problem constants: E=4 edge types, B=262144 tokens, C=128 dim
#define N_E 4
#define N_B 262144
#define N_C 128

typedef __attribute__((ext_vector_type(8))) short bf16x8;    // MFMA A/B frag (8 bf16)
typedef __attribute__((ext_vector_type(4))) float f32x4;
typedef __attribute__((ext_vector_type(16))) float f32x16;   // 32x32 MFMA C/D frag
typedef __attribute__((ext_vector_type(4))) unsigned int u32x4;

// pack two fp32 -> u32 of 2 bf16 (RNE) via v_cvt_pk_bf16_f32
__device__ __forceinline__ unsigned pk2(float lo, float hi) {
  float2 t; t.x = lo; t.y = hi;
  __hip_bfloat162 h = __float22bfloat162_rn(t);
  union { __hip_bfloat162 h; unsigned u; } c;
  c.h = h;
  return c.u;
}

// out[b][d] = sum_e sum_c xs[e][b][c]*Ws[e][c][d] + sum_e bs[e][d]
// M=262144, N=128, K=512; memory-bound.
//
// R1-R8: all global-side hypotheses null; every version shared the SAME inner
// recipe: 8 ds_read_b128 + 8 MFMA(16x16x32) + 4 cvt_pk per 1KB of A. Per-CU:
// LDS pipe ~82us busy (>55%), coupled in series with the vmcnt-ordered load
// pipeline -> queueing starves load issue. This round: 32x32x16 MFMA. Wave
// tile = 32 rows x 128 cols; per 16-k step one ds_read_b128 per 32-col group
// = 4 ds_reads per 2KB of A (4x fewer LDS instr/byte; LDS busy -> ~20us),
// cvt_pk halved, MFMA cyc/byte 2.4x down. Same k-bijection trick on both
// operands (validated R4/R7/R8): A lane (row=l&31, h=l>>5) holds k =
// kt*16 + h*8 + j, contiguous 32B per (e,kt); W LDS entries permuted to match.
// 6-deep per-wave load pipeline, hand-counted vmcnt, sched_barrier(0) after
// each wait (rule #18). One barrier total. C/D: col=lane&31,
// row=(reg&3)+8*(reg>>2)+4*(lane>>5) [m74/m101].
__global__ void __launch_bounds__(512, 2)
grouped_gemm(const float* __restrict__ xs, const float* __restrict__ Ws,
             const float* __restrict__ bs, float* __restrict__ out) {
  extern __shared__ unsigned char smem[];
  unsigned short* lds_w = (unsigned short*)smem;  // 8192 entries * 16B = 128 KiB

  const int tid  = threadIdx.x;
  const int lane = tid & 63;
  const int wave = tid >> 6;       // 0..7
  const int col5 = lane & 31;      // col within 32-col group / A row
  const int h    = lane >> 5;      // 0..1: k-half
  const int waveRow = blockIdx.x * 256 + wave * 32;

  // ---- bias -> registers (retires before the pipeline region) ----
  float bias[4];
#pragma unroll
  for (int n = 0; n < 4; ++n) {
    int d = n * 32 + col5;
    bias[n] = bs[d] + bs[128 + d] + bs[256 + d] + bs[384 + d];
  }

  // ---- stage ALL W (4x128x128 fp32) -> LDS bf16, 32x32-fragment layout ----
  // entry m: e=m>>11, kt=(m>>8)&7, n=(m>>6)&3, h2=(m>>5)&1, col=m&31.
  // 8 shorts j=0..7 hold W[e][kt*16 + h2*8 + j][n*32+col]  (matches A k-map).
  // Reader for (e,kt,n): lane l reads entry ((e*8+kt)*4+n)*64 + l  -> byte
  // base + l*16: fully linear, 2-way bank alias only (free, m136).
#pragma unroll
  for (int i = 0; i < 16; ++i) {
    int m = tid + i * 512;
    int e  = m >> 11;
    int kt = (m >> 8) & 7;
    int n  = (m >> 6) & 3;
    int h2 = (m >> 5) & 1;
    int c5 = m & 31;
    const float* src = Ws + e * (N_C * N_C) + (kt * 16 + h2 * 8) * N_C + n * 32 + c5;
    float v[8];
#pragma unroll
    for (int j = 0; j < 8; ++j) v[j] = src[j * N_C];
    u32x4 pk;
#pragma unroll
    for (int j = 0; j < 4; ++j) pk[j] = pk2(v[2 * j], v[2 * j + 1]);
    *reinterpret_cast<u32x4*>(&lds_w[(size_t)m * 8]) = pk;
  }

  // Drain ALL compiler-emitted vmem (bias + W gather) so loop vmcnt counts are exact.
  asm volatile("s_waitcnt vmcnt(0)" ::: "memory");
  __syncthreads();  // the only barrier

  // ---- A stream: 32 chunks s (e=s>>3, kt=s&7) ----
  // lane (col5=row, h): 32B at row*512 + e*128MB + kt*64 + h*32  (k=kt*16+h*8+j)
  const unsigned vb = (unsigned)(waveRow + col5) * 512u + (unsigned)h * 32u;
  const unsigned long long xbase = (unsigned long long)xs;

  f32x4 A0[6], A1[6];  // 6-deep rotating buffer (statically indexed only)

#define AISSUE(s)                                                              \
  do {                                                                         \
    unsigned o;                                                                \
    asm volatile("v_add_u32 %0, %1, %2"                                        \
                 : "=v"(o)                                                     \
                 : "n"((((s) >> 3) * 134217728u) + (((s) & 7) * 64u)), "v"(vb)); \
    asm volatile("global_load_dwordx4 %0, %2, %3 offset:0\n\t"                 \
                 "global_load_dwordx4 %1, %2, %3 offset:16"                    \
                 : "=&v"(A0[(s) % 6]), "=&v"(A1[(s) % 6])                      \
                 : "v"(o), "s"(xbase)                                          \
                 : "memory");                                                  \
  } while (0)

#define WAITV(n)                                          \
  do {                                                    \
    asm volatile("s_waitcnt vmcnt(" #n ")" ::: "memory"); \
    __builtin_amdgcn_sched_barrier(0);                    \
  } while (0)

  f32x16 acc[4];
#pragma unroll
  for (int n = 0; n < 4; ++n) {
#pragma unroll
    for (int r = 0; r < 16; ++r) acc[n][r] = 0.0f;
  }

  // STEP(s,w): wait chunk s, cvt to bf16, refill slot s+6, 4 x MFMA 32x32x16.
#define STEP(s, w)                                                             \
  do {                                                                         \
    WAITV(w);                                                                  \
    f32x4 a0 = A0[(s) % 6];                                                    \
    f32x4 a1 = A1[(s) % 6];                                                    \
    bf16x8 afrag;                                                              \
    unsigned* au = reinterpret_cast<unsigned*>(&afrag);                        \
    au[0] = pk2(a0[0], a0[1]);                                                 \
    au[1] = pk2(a0[2], a0[3]);                                                 \
    au[2] = pk2(a1[0], a1[1]);                                                 \
    au[3] = pk2(a1[2], a1[3]);                                                 \
    if ((s) <= 25) AISSUE((s) + 6);                                            \
    const unsigned short* wb =                                                 \
        lds_w + ((size_t)((((s) >> 3) * 8 + ((s) & 7)) * 4) * 64 + lane) * 8;  \
    _Pragma("unroll")                                                          \
    for (int n = 0; n < 4; ++n) {                                              \
      bf16x8 bfrag = *reinterpret_cast<const bf16x8*>(wb + (size_t)n * 512);   \
      acc[n] = __builtin_amdgcn_mfma_f32_32x32x16_bf16(afrag, bfrag, acc[n], 0, 0, 0); \
    }                                                                          \
  } while (0)

  AISSUE(0); AISSUE(1); AISSUE(2); AISSUE(3); AISSUE(4); AISSUE(5);

  // steady state: 12 loads outstanding at entry; wait(10) retires the 2 oldest
  STEP(0, 10);  STEP(1, 10);  STEP(2, 10);  STEP(3, 10);
  STEP(4, 10);  STEP(5, 10);  STEP(6, 10);  STEP(7, 10);
  STEP(8, 10);  STEP(9, 10);  STEP(10, 10); STEP(11, 10);
  STEP(12, 10); STEP(13, 10); STEP(14, 10); STEP(15, 10);
  STEP(16, 10); STEP(17, 10); STEP(18, 10); STEP(19, 10);
  STEP(20, 10); STEP(21, 10); STEP(22, 10); STEP(23, 10);
  STEP(24, 10); STEP(25, 10); STEP(26, 10);
  // tail: no more issues; queue shrinks 12 -> 0
  STEP(27, 8);  STEP(28, 6);  STEP(29, 4);  STEP(30, 2);  STEP(31, 0);

#undef STEP
#undef WAITV
#undef AISSUE

  // ---- epilogue: + bias, store. C/D: col=lane&31, row=(reg&3)+8*(reg>>2)+4*h ----
#pragma unroll
  for (int n = 0; n < 4; ++n) {
    int d = n * 32 + col5;
#pragma unroll
    for (int r = 0; r < 16; ++r) {
      int row = waveRow + (r & 3) + 8 * (r >> 2) + 4 * h;
      out[(size_t)row * N_C + d] = acc[n][r] + bias[n];
    }
  }
}

extern "C" void kernel_launch(void* const* d_in, const int* in_sizes, int n_in,
                              void* d_out, int out_size, void* d_ws, size_t ws_size,
                              hipStream_t stream) {
  const float* xs = (const float*)d_in[0];  // [4][262144][128] fp32
  const float* Ws = (const float*)d_in[1];  // [4][128][128] fp32
  const float* bs = (const float*)d_in[2];  // [4][128] fp32
  float* out = (float*)d_out;               // [262144][128] fp32

  const size_t smem = 131072;  // W bf16 32x32-frag layout, all 4 edge types
  hipFuncSetAttribute((const void*)grouped_gemm,
                      hipFuncAttributeMaxDynamicSharedMemorySize, (int)smem);

  dim3 grid(N_B / 256);   // 1024 blocks (256 rows each)
  dim3 block(512);        // 8 waves -> 8 waves/CU (1 block/CU via 128 KiB LDS)
  hipLaunchKernelGGL(grouped_gemm, grid, block, smem, stream, xs, Ws, bs, out);
}

// Round 10
// 138.615 us; speedup vs baseline: 1.1018x; 1.0596x over previous
//
#include <hip/hip_runtime.h>
#include <hip/hip_bf16.h>

// Problem constants: E=4 edge types, B=262144 tokens, C=128 dim
#define N_E 4
#define N_B 262144
#define N_C 128

typedef __attribute__((ext_vector_type(8))) short bf16x8;   // MFMA A/B frag (8 bf16)
typedef __attribute__((ext_vector_type(4))) float f32x4;    // MFMA C/D frag
typedef __attribute__((ext_vector_type(4))) unsigned int u32x4;

// pack two fp32 -> u32 of 2 bf16 (RNE) via v_cvt_pk_bf16_f32
__device__ __forceinline__ unsigned pk2(float lo, float hi) {
  float2 t; t.x = lo; t.y = hi;
  __hip_bfloat162 h = __float22bfloat162_rn(t);
  union { __hip_bfloat162 h; unsigned u; } c;
  c.h = h;
  return c.u;
}

// out[b][d] = sum_e sum_c xs[e][b][c]*Ws[e][c][d] + sum_e bs[e][d]
// M=262144, N=128, K=512; memory-bound. R1-R9 establish the read path as the
// wall (~3.7 TB/s read rate; m13 copy's read side = 3.15 TB/s). This round
// removes the two remaining dead-time components, load pattern untouched:
//  (a) EARLY ISSUE: pipeline chunks 0-3 are issued BEFORE the W-gather, so
//      128 KB/CU of xs streams concurrently with the L2-bound W prologue.
//      They are the oldest entries in the vmcnt FIFO and the pre-barrier
//      vmcnt(0) retires them; wait table unchanged (6 x13, 4, 2, 0).
//  (b) SWAPPED-OPERAND MFMA: mfma(Wfrag, xfrag, acc) -> D is d-major per
//      lane (m=d, n=token); epilogue = 8x global_store_dwordx4 per wave-tile
//      (64B runs) instead of 32 scalar stores. Bias added from LDS.
// Pipeline otherwise = R4: 16 waves/CU, 4-deep rotating register buffer,
// hand-counted vmcnt, sched_barrier(0) after each wait, one barrier total.
__global__ void __launch_bounds__(1024, 4)
grouped_gemm(const float* __restrict__ xs, const float* __restrict__ Ws,
             const float* __restrict__ bs, float* __restrict__ out) {
  extern __shared__ unsigned char smem[];
  unsigned short* lds_w    = (unsigned short*)smem;    // 8192 entries * 16B = 128 KiB
  float*          lds_bias = (float*)(smem + 131072);  // 512 B

  const int tid  = threadIdx.x;
  const int lane = tid & 63;
  const int wave = tid >> 6;       // 0..15
  const int l15  = lane & 15;
  const int hi   = lane >> 4;
  const int waveRow = blockIdx.x * 256 + wave * 16;

  // ---- A-stream geometry (needed for early issue) ----
  const unsigned vb = (unsigned)(waveRow + l15) * 512u + (unsigned)hi * 32u;
  const unsigned long long xbase = (unsigned long long)xs;

  f32x4 A0[4], A1[4];  // 4-deep rotating chunk buffer (statically indexed only)

#define AISSUE(c)                                                              \
  do {                                                                         \
    unsigned o;                                                                \
    asm volatile("v_add_u32 %0, %1, %2"                                        \
                 : "=v"(o)                                                     \
                 : "n"(((c) >> 2) * 134217728u + ((c) & 3) * 128u), "v"(vb));  \
    asm volatile("global_load_dwordx4 %0, %2, %3 offset:0\n\t"                 \
                 "global_load_dwordx4 %1, %2, %3 offset:16"                    \
                 : "=&v"(A0[(c) & 3]), "=&v"(A1[(c) & 3])                      \
                 : "v"(o), "s"(xbase)                                          \
                 : "memory");                                                  \
  } while (0)

#define WAITV(n)                                          \
  do {                                                    \
    asm volatile("s_waitcnt vmcnt(" #n ")" ::: "memory"); \
    __builtin_amdgcn_sched_barrier(0);                    \
  } while (0)

  // ---- EARLY ISSUE: chunks 0-3 in flight during the whole W prologue ----
  AISSUE(0); AISSUE(1); AISSUE(2); AISSUE(3);

  // ---- stage ALL W (4x128x128 fp32) -> LDS bf16 fragment layout (once) ----
  // entry m: e=m>>11, u=(m>>7)&15, d=m&127 ; holds Ws[e][u*8+j][d], j=0..7 (16B)
  // (asm volatile "memory" above keeps these loads AFTER the xs issues in the FIFO)
#pragma unroll
  for (int i = 0; i < 8; ++i) {
    int m = tid + i * 1024;
    int e = m >> 11;
    int u = (m >> 7) & 15;
    int d = m & 127;
    const float* src = Ws + e * (N_C * N_C) + u * 8 * N_C + d;
    float v[8];
#pragma unroll
    for (int j = 0; j < 8; ++j) v[j] = src[j * N_C];
    u32x4 pk;
#pragma unroll
    for (int j = 0; j < 4; ++j) pk[j] = pk2(v[2 * j], v[2 * j + 1]);
    *reinterpret_cast<u32x4*>(&lds_w[(size_t)m * 8]) = pk;
  }
  if (tid < 128) {
    lds_bias[tid] = bs[tid] + bs[128 + tid] + bs[256 + tid] + bs[384 + tid];
  }

  // Drain ALL vmem (early xs chunks 0-3 + W gather + bias) -> registers/LDS valid,
  // vmcnt FIFO empty, so loop counts below are exact.
  asm volatile("s_waitcnt vmcnt(0)" ::: "memory");
  __syncthreads();  // the only barrier

  f32x4 acc[8];
#pragma unroll
  for (int n = 0; n < 8; ++n) {
    f32x4 z = {0.0f, 0.0f, 0.0f, 0.0f};
    acc[n] = z;
  }

  // STEP(s): wait chunk s, cvt, refill slot s+4, 8 x mfma(W, x, acc).
  // Swapped operands: A=W (m-dim = d), B=x (n-dim = token). Both frags use the
  // same k-map (k = kt*32 + hi*8 + j == u*8 + j with u = kt*4+hi) -> exact.
#define STEP(s, w)                                                             \
  do {                                                                         \
    WAITV(w);                                                                  \
    f32x4 a0 = A0[(s) & 3];                                                    \
    f32x4 a1 = A1[(s) & 3];                                                    \
    bf16x8 xfrag;                                                              \
    unsigned* au = reinterpret_cast<unsigned*>(&xfrag);                        \
    au[0] = pk2(a0[0], a0[1]);                                                 \
    au[1] = pk2(a0[2], a0[3]);                                                 \
    au[2] = pk2(a1[0], a1[1]);                                                 \
    au[3] = pk2(a1[2], a1[3]);                                                 \
    if ((s) <= 11) AISSUE((s) + 4);                                            \
    const unsigned short* wb =                                                 \
        lds_w + (size_t)((((s) >> 2) * 16 + ((s) & 3) * 4 + hi) * 128 + l15) * 8; \
    _Pragma("unroll")                                                          \
    for (int n = 0; n < 8; ++n) {                                              \
      bf16x8 wfrag = *reinterpret_cast<const bf16x8*>(wb + (size_t)n * 128);   \
      acc[n] = __builtin_amdgcn_mfma_f32_16x16x32_bf16(wfrag, xfrag, acc[n], 0, 0, 0); \
    }                                                                          \
  } while (0)

  // chunks 0-3 already resident (early issue) -> waits are no-ops by count;
  // steady state 8 outstanding -> wait(6); tail drains 6/4/2/0.
  STEP(0, 6);  STEP(1, 6);  STEP(2, 6);  STEP(3, 6);
  STEP(4, 6);  STEP(5, 6);  STEP(6, 6);  STEP(7, 6);
  STEP(8, 6);  STEP(9, 6);  STEP(10, 6); STEP(11, 6);
  STEP(12, 6); STEP(13, 4); STEP(14, 2); STEP(15, 0);

#undef STEP
#undef WAITV
#undef AISSUE

  // ---- epilogue: D[m=d][n=token]; lane (l15,hi): token=waveRow+l15,
  // d = n*16 + hi*4 + r -> one dwordx4 per n (64B runs per output row).
  {
    float* ob = out + (size_t)(waveRow + l15) * N_C + hi * 4;
#pragma unroll
    for (int n = 0; n < 8; ++n) {
      f32x4 bv = *reinterpret_cast<const f32x4*>(&lds_bias[n * 16 + hi * 4]);
      f32x4 v = acc[n] + bv;
      *reinterpret_cast<f32x4*>(ob + n * 16) = v;
    }
  }
}

extern "C" void kernel_launch(void* const* d_in, const int* in_sizes, int n_in,
                              void* d_out, int out_size, void* d_ws, size_t ws_size,
                              hipStream_t stream) {
  const float* xs = (const float*)d_in[0];  // [4][262144][128] fp32
  const float* Ws = (const float*)d_in[1];  // [4][128][128] fp32
  const float* bs = (const float*)d_in[2];  // [4][128] fp32
  float* out = (float*)d_out;               // [262144][128] fp32

  const size_t smem = 131072 + 512;  // W frag layout + bias
  hipFuncSetAttribute((const void*)grouped_gemm,
                      hipFuncAttributeMaxDynamicSharedMemorySize, (int)smem);

  dim3 grid(N_B / 256);   // 1024 blocks (256 rows each), 4 generations/CU
  dim3 block(1024);       // 16 waves -> 16 waves/CU
  hipLaunchKernelGGL(grouped_gemm, grid, block, smem, stream, xs, Ws, bs, out);
}